// Round 17
// baseline (218.642 us; speedup 1.0000x reference)
//
#include <hip/hip_runtime.h>
#include <stdint.h>

// Problem constants (B=4, S=2048 -> M = 8192 rows)
#define M_TOT 8192
#define N_TOT 4096
#define K_TOT 4096

typedef int v4i __attribute__((ext_vector_type(4)));

// GEMM tile config: 256x128 tile, K-step 64 B, FOUR waves (2M x 2N), 256 thr.
// Per-wave output 128x64 (identical to R12's per-wave geometry/acc budget),
// but block = 4 waves -> TWO blocks co-resident per CU (2 waves/SIMD x 240
// regs fits the 512-reg/SIMD pool; LDS 72 KB x 2 = 144 <= 160 KB).
// The co-resident block's MFMA hides this block's barrier/drain (m114 TLP).
#define BM 256
#define BN 128
#define SUB 64
#define NS (K_TOT / SUB)                  // 64 sub-tile iterations
#define A_SUB (BM * SUB)                  // 16 KB
#define B_SUB (BN * SUB)                  // 8 KB
#define BUF_BYTES (A_SUB + B_SUB)         // 24 KB; x3 buffers = 72 KB LDS

#define NPREP 2048                        // prep_reduce grid = partials count

// ---------------------------------------------------------------------------
// Kernel 1: pack weight int32->int8 + per-block max(|x/smooth|) -> partials.
// (R12 verbatim — pre-phase measured at its HBM floor.)
// ---------------------------------------------------------------------------
__global__ void prep_reduce(const int4* __restrict__ w32, int* __restrict__ w8,
                            int nw4, const float4* __restrict__ smooth4,
                            const float4* __restrict__ x,
                            float* __restrict__ partials, int nx4) {
  const int stride = gridDim.x * blockDim.x;
  const int g0 = blockIdx.x * blockDim.x + threadIdx.x;
  for (int i = g0; i < nw4; i += stride) {
    int4 v = w32[i];
    w8[i] = (v.x & 0xff) | ((v.y & 0xff) << 8) | ((v.z & 0xff) << 16) | (v.w << 24);
  }
  float4 s = smooth4[g0 & (K_TOT / 4 - 1)];
  const float rx = 1.0f / s.x, ry = 1.0f / s.y, rz = 1.0f / s.z, rw = 1.0f / s.w;
  float m = 0.0f;
  for (int i = g0; i < nx4; i += stride) {
    float4 v = x[i];
    m = fmaxf(m, fabsf(v.x * rx));
    m = fmaxf(m, fabsf(v.y * ry));
    m = fmaxf(m, fabsf(v.z * rz));
    m = fmaxf(m, fabsf(v.w * rw));
  }
#pragma unroll
  for (int off = 32; off; off >>= 1) m = fmaxf(m, __shfl_xor(m, off));
  __shared__ float sm[4];
  if ((threadIdx.x & 63) == 0) sm[threadIdx.x >> 6] = m;
  __syncthreads();
  if (threadIdx.x == 0) {
    partials[blockIdx.x] = fmaxf(fmaxf(sm[0], sm[1]), fmaxf(sm[2], sm[3]));
  }
}

// ---------------------------------------------------------------------------
// Kernel 2: reduce partials (every block) -> inv scale; quantize x -> int8.
// (R12 verbatim.)
// ---------------------------------------------------------------------------
__global__ void quantize_x(const float4* __restrict__ x,
                           const float4* __restrict__ smooth4,
                           const float* __restrict__ partials,
                           unsigned int* __restrict__ maxbits,
                           int* __restrict__ xq, int n4) {
  float m = 0.0f;
  for (int i = threadIdx.x; i < NPREP; i += blockDim.x) m = fmaxf(m, partials[i]);
#pragma unroll
  for (int off = 32; off; off >>= 1) m = fmaxf(m, __shfl_xor(m, off));
  __shared__ float sm[4];
  __shared__ float s_inv;
  if ((threadIdx.x & 63) == 0) sm[threadIdx.x >> 6] = m;
  __syncthreads();
  if (threadIdx.x == 0) {
    float mm = fmaxf(fmaxf(sm[0], sm[1]), fmaxf(sm[2], sm[3]));
    if (blockIdx.x == 0) *maxbits = __float_as_uint(mm);   // for gemm epilogue
    s_inv = 1.0f / (mm / 127.0f + 1e-5f);
  }
  __syncthreads();
  const float inv = s_inv;

  const int stride = gridDim.x * blockDim.x;
  const int g0 = blockIdx.x * blockDim.x + threadIdx.x;
  float4 s = smooth4[g0 & (K_TOT / 4 - 1)];
  const float rx = inv / s.x, ry = inv / s.y, rz = inv / s.z, rw = inv / s.w;
  for (int i = g0; i < n4; i += stride) {
    float4 v = x[i];
    int q0 = (int)fminf(fmaxf(rintf(v.x * rx), -128.0f), 127.0f);
    int q1 = (int)fminf(fmaxf(rintf(v.y * ry), -128.0f), 127.0f);
    int q2 = (int)fminf(fmaxf(rintf(v.z * rz), -128.0f), 127.0f);
    int q3 = (int)fminf(fmaxf(rintf(v.w * rw), -128.0f), 127.0f);
    xq[i] = (q0 & 0xff) | ((q1 & 0xff) << 8) | ((q2 & 0xff) << 16) | (q3 << 24);
  }
}

// ---------------------------------------------------------------------------
// Kernel 3: int8 GEMM — R12 loop body (b-first reads, stage-after-reads, one
// barrier/iter, verified swizzle) at 4-wave blocks for 2-blocks/CU TLP.
//
// Race-freedom (iteration s, reading buf[s%3]):
//   * stage targets buf[(s+2)%3] = buf[(s-1)%3]: its reads completed before
//     iter s-1's end barrier (lgkmcnt(0) precedes it). No write-under-read.
//   * stage = 6 DMA/wave (4 A + 2 B). At iter-s end outstanding = tile s+1's
//     6 (issued iter s-1) + tile s+2's 6 (issued iter s) = 12; vmcnt(6)
//     drains the OLDEST 6 = tile s+1; barrier publishes. Prologue: stage
//     tiles 0,1 (12 ops), vmcnt(6) drains tile 0. vmcnt never 0 (T4).
//
// LDS swizzle (T2, 64-B rows) — MEASURED 0 CONFLICTS, do not modify:
//   read slot = (lhi ^ ((l16>>1)&3))*16; stage gcol = ((lane&3)^((lane>>3)&3))*16
// ---------------------------------------------------------------------------
__global__ __launch_bounds__(256, 2) void gemm_i8(
    const int8_t* __restrict__ Aq,   // [M][K]
    const int8_t* __restrict__ Wt,   // [N][K]
    const unsigned int* __restrict__ maxbits,
    const float* __restrict__ wscale,  // [N]
    const float* __restrict__ bias,    // [N]
    float* __restrict__ out) {         // [M][N]
  __shared__ int8_t lds[3 * BUF_BYTES];

  const int tid = threadIdx.x;
  const int lane = tid & 63;
  const int wid = tid >> 6;      // 0..3
  const int l16 = lane & 15;
  const int lhi = lane >> 4;     // 0..3

  // T1: XCD-aware block swizzle. 1024 blocks, 1024 % 8 == 0 -> bijective.
  const int flat = blockIdx.y * gridDim.x + blockIdx.x;
  const int swz = (flat & 7) * 128 + (flat >> 3);
  const int m0 = (swz / (N_TOT / BN)) * BM;
  const int n0 = (swz % (N_TOT / BN)) * BN;

  const int wave_m = wid >> 1;   // 0..1  -> 128 rows
  const int wave_n = wid & 1;    // 0..1  -> 64 cols

  // ---- staging: per wave 4 A-chunks + 2 B-chunks, 1 KB each (16 rows x 64B)
  const int row_l = lane >> 2;                             // row in chunk 0..15
  const int gcol = ((lane & 3) ^ ((lane >> 3) & 3)) << 4;  // pre-swizzled slot
  const int8_t* Abase = Aq + (size_t)m0 * K_TOT;           // uniform
  const int8_t* Bbase = Wt + (size_t)n0 * K_TOT;           // uniform
  int goffA[4], goffB[2];
#pragma unroll
  for (int c = 0; c < 4; ++c) {
    int grow = (wid * 4 + c) * 16 + row_l;                 // 0..255
    goffA[c] = grow * K_TOT + gcol;
  }
#pragma unroll
  for (int c = 0; c < 2; ++c) {
    int grow = (wid * 2 + c) * 16 + row_l;                 // 0..127
    goffB[c] = grow * K_TOT + gcol;
  }

  auto stage = [&](int dstbuf, int koff) {
#pragma unroll
    for (int c = 0; c < 4; ++c) {
      __builtin_amdgcn_global_load_lds(
          (const __attribute__((address_space(1))) void*)(Abase + goffA[c] + koff),
          (__attribute__((address_space(3))) void*)(lds + dstbuf * BUF_BYTES + (wid * 4 + c) * 1024),
          16, 0, 0);
    }
#pragma unroll
    for (int c = 0; c < 2; ++c) {
      __builtin_amdgcn_global_load_lds(
          (const __attribute__((address_space(1))) void*)(Bbase + goffB[c] + koff),
          (__attribute__((address_space(3))) void*)(lds + dstbuf * BUF_BYTES + A_SUB + (wid * 2 + c) * 1024),
          16, 0, 0);
    }
  };

  // ---- ds_read fragment addressing (swizzled, 64-B rows) ----
  const int slot = (lhi ^ ((l16 >> 1) & 3)) << 4;
  const int aOff = (wave_m * 128 + l16) * SUB + slot;
  const int bOff = (wave_n * 64 + l16) * SUB + slot;

  // ---- prologue: stage sub-tiles 0,1; drain sub-tile 0 ----
  stage(0, 0);
  stage(1, SUB);
  asm volatile("s_waitcnt vmcnt(6)" ::: "memory");
  __builtin_amdgcn_s_barrier();
  __builtin_amdgcn_sched_barrier(0);

  v4i acc[8][4] = {};

  int buf = 0;
  for (int s = 0; s < NS; ++s) {
    const int8_t* Ab = lds + buf * BUF_BYTES;
    const int8_t* Bb = Ab + A_SUB;
    const int stg = (buf + 2 > 2) ? (buf - 1) : (buf + 2);   // (buf+2)%3

    // 12 ds_read_b128 — b's FIRST so MFMA group 0 is eligible after 5 reads
    v4i a[8], b[4];
#pragma unroll
    for (int j = 0; j < 4; ++j) b[j] = *(const v4i*)(Bb + bOff + j * 1024);
#pragma unroll
    for (int i = 0; i < 8; ++i) a[i] = *(const v4i*)(Ab + aOff + i * 1024);

    // prefetch sub-tile s+2 into the buffer whose reads finished at iter s-1
    const int ts = (s + 2 < NS) ? (s + 2) : (NS - 1);
    stage(stg, ts * SUB);

    __builtin_amdgcn_s_setprio(1);
#pragma unroll
    for (int i = 0; i < 8; ++i)
#pragma unroll
      for (int j = 0; j < 4; ++j)
        acc[i][j] = __builtin_amdgcn_mfma_i32_16x16x64_i8(a[i], b[j], acc[i][j], 0, 0, 0);
    __builtin_amdgcn_s_setprio(0);
    __builtin_amdgcn_sched_barrier(0);

    asm volatile("s_waitcnt lgkmcnt(0)" ::: "memory");
    asm volatile("s_waitcnt vmcnt(6)" ::: "memory");
    __builtin_amdgcn_sched_barrier(0);
    __builtin_amdgcn_s_barrier();
    __builtin_amdgcn_sched_barrier(0);

    buf = (buf + 1 > 2) ? 0 : (buf + 1);
  }

  // ---- epilogue: dequant + bias, C/D layout col=l16, row=lhi*4+reg ----
  const float ascale = __uint_as_float(*maxbits) / 127.0f;
#pragma unroll
  for (int i = 0; i < 8; ++i) {
    const int orow = m0 + wave_m * 128 + i * 16 + lhi * 4;
#pragma unroll
    for (int j = 0; j < 4; ++j) {
      const int ocol = n0 + wave_n * 64 + j * 16 + l16;
      const float wsc = wscale[ocol] * ascale;
      const float bb = bias[ocol];
#pragma unroll
      for (int r = 0; r < 4; ++r) {
        out[(size_t)(orow + r) * N_TOT + ocol] = (float)acc[i][j][r] * wsc + bb;
      }
    }
  }
}

// ---------------------------------------------------------------------------
extern "C" void kernel_launch(void* const* d_in, const int* in_sizes, int n_in,
                              void* d_out, int out_size, void* d_ws, size_t ws_size,
                              hipStream_t stream) {
  const float* x = (const float*)d_in[0];
  const int* w32 = (const int*)d_in[1];        // int8 in reference, int32 on device
  const float* wscale = (const float*)d_in[2];
  const float* smooth = (const float*)d_in[3];
  const float* bias = (const float*)d_in[4];
  float* out = (float*)d_out;

  unsigned int* maxbits = (unsigned int*)d_ws;
  float* partials = (float*)((char*)d_ws + 1024);            // NPREP floats
  int8_t* xq = (int8_t*)d_ws + (1 << 20);                    // 32 MB
  int8_t* wq8 = xq + (size_t)M_TOT * K_TOT;                  // 16 MB

  const int nw4 = N_TOT * K_TOT / 4;
  const int n4 = M_TOT * K_TOT / 4;
  prep_reduce<<<NPREP, 256, 0, stream>>>((const int4*)w32, (int*)wq8, nw4,
                                         (const float4*)smooth, (const float4*)x,
                                         partials, n4);
  quantize_x<<<2048, 256, 0, stream>>>((const float4*)x, (const float4*)smooth,
                                       partials, maxbits, (int*)xq, n4);

  dim3 grid(N_TOT / BN, M_TOT / BM);
  gemm_i8<<<grid, 256, 0, stream>>>(xq, wq8, maxbits, wscale, bias, out);
}

// Round 18
// 203.142 us; speedup vs baseline: 1.0763x; 1.0763x over previous
//
#include <hip/hip_runtime.h>
#include <stdint.h>

// Problem constants (B=4, S=2048 -> M = 8192 rows)
#define M_TOT 8192
#define N_TOT 4096
#define K_TOT 4096

typedef int v4i __attribute__((ext_vector_type(4)));

// GEMM tile config: 256x256 tile, sub-tile K-step = 64 B, 8 waves (2M x 4N)
#define BM 256
#define BN 256
#define SUB 64
#define NS (K_TOT / SUB)                  // 64 sub-tile iterations
#define A_SUB (BM * SUB)                  // 16 KB
#define B_SUB (BN * SUB)                  // 16 KB
#define BUF_BYTES (A_SUB + B_SUB)         // 32 KB; x4 buffers = 128 KB LDS

#define NPREP 2048                        // prep_reduce grid = partials count

// ---------------------------------------------------------------------------
// Kernel 1: pack weight int32->int8 + per-block max(|x/smooth|) -> partials.
// No atomics, no init required (all NPREP entries written every call).
// Grid stride (524288) is a multiple of K/4=1024 -> smooth slice loop-invariant.
// ---------------------------------------------------------------------------
__global__ void prep_reduce(const int4* __restrict__ w32, int* __restrict__ w8,
                            int nw4, const float4* __restrict__ smooth4,
                            const float4* __restrict__ x,
                            float* __restrict__ partials, int nx4) {
  const int stride = gridDim.x * blockDim.x;
  const int g0 = blockIdx.x * blockDim.x + threadIdx.x;
  for (int i = g0; i < nw4; i += stride) {
    int4 v = w32[i];
    w8[i] = (v.x & 0xff) | ((v.y & 0xff) << 8) | ((v.z & 0xff) << 16) | (v.w << 24);
  }
  float4 s = smooth4[g0 & (K_TOT / 4 - 1)];
  const float rx = 1.0f / s.x, ry = 1.0f / s.y, rz = 1.0f / s.z, rw = 1.0f / s.w;
  float m = 0.0f;
  for (int i = g0; i < nx4; i += stride) {
    float4 v = x[i];
    m = fmaxf(m, fabsf(v.x * rx));
    m = fmaxf(m, fabsf(v.y * ry));
    m = fmaxf(m, fabsf(v.z * rz));
    m = fmaxf(m, fabsf(v.w * rw));
  }
#pragma unroll
  for (int off = 32; off; off >>= 1) m = fmaxf(m, __shfl_xor(m, off));
  __shared__ float sm[4];
  if ((threadIdx.x & 63) == 0) sm[threadIdx.x >> 6] = m;
  __syncthreads();
  if (threadIdx.x == 0) {
    partials[blockIdx.x] = fmaxf(fmaxf(sm[0], sm[1]), fmaxf(sm[2], sm[3]));
  }
}

// ---------------------------------------------------------------------------
// Kernel 2: reduce partials (every block, identical result) -> inv scale;
// block 0 stores maxbits for the GEMM epilogue; then quantize x -> int8.
// rinv = (1/s) * inv hoisted per thread (grid stride multiple of K/4).
// ---------------------------------------------------------------------------
__global__ void quantize_x(const float4* __restrict__ x,
                           const float4* __restrict__ smooth4,
                           const float* __restrict__ partials,
                           unsigned int* __restrict__ maxbits,
                           int* __restrict__ xq, int n4) {
  float m = 0.0f;
  for (int i = threadIdx.x; i < NPREP; i += blockDim.x) m = fmaxf(m, partials[i]);
#pragma unroll
  for (int off = 32; off; off >>= 1) m = fmaxf(m, __shfl_xor(m, off));
  __shared__ float sm[4];
  __shared__ float s_inv;
  if ((threadIdx.x & 63) == 0) sm[threadIdx.x >> 6] = m;
  __syncthreads();
  if (threadIdx.x == 0) {
    float mm = fmaxf(fmaxf(sm[0], sm[1]), fmaxf(sm[2], sm[3]));
    if (blockIdx.x == 0) *maxbits = __float_as_uint(mm);   // for gemm epilogue
    s_inv = 1.0f / (mm / 127.0f + 1e-5f);
  }
  __syncthreads();
  const float inv = s_inv;

  const int stride = gridDim.x * blockDim.x;
  const int g0 = blockIdx.x * blockDim.x + threadIdx.x;
  float4 s = smooth4[g0 & (K_TOT / 4 - 1)];
  const float rx = inv / s.x, ry = inv / s.y, rz = inv / s.z, rw = inv / s.w;
  for (int i = g0; i < n4; i += stride) {
    float4 v = x[i];
    int q0 = (int)fminf(fmaxf(rintf(v.x * rx), -128.0f), 127.0f);
    int q1 = (int)fminf(fmaxf(rintf(v.y * ry), -128.0f), 127.0f);
    int q2 = (int)fminf(fmaxf(rintf(v.z * rz), -128.0f), 127.0f);
    int q3 = (int)fminf(fmaxf(rintf(v.w * rw), -128.0f), 127.0f);
    xq[i] = (q0 & 0xff) | ((q1 & 0xff) << 8) | ((q2 & 0xff) << 16) | (q3 << 24);
  }
}

// ---------------------------------------------------------------------------
// Kernel 3: int8 GEMM — R12 VERBATIM, the verified optimum (132.2 us,
// MfmaUtil 47.8%, SQ_LDS_BANK_CONFLICT == 0). 256x256 tile, 64-B K-sub-tiles,
// 4-buffer / 3-deep counted-vmcnt pipeline, ONE barrier per sub-tile,
// b-first ds_reads, stage-after-reads.
//
// Occupancy is a HARD 1 block/CU at this accumulator footprint (240 unified
// regs/wave): fat-acc (R14) and forced waves/EU (R15) spill; 4-wave narrow
// blocks (R17) don't co-schedule. Co-limit: LDS-port ~1150 cyc/iter vs MFMA
// ~1306 cyc/iter with ~60% overlap -> ~132 us is this structure's floor.
//
// Race-freedom (iteration s, reading buf[s&3]):
//   * stage targets buf[(s+3)&3] = buf[(s-1)&3]: reads completed before iter
//     s-1's end barrier (lgkmcnt(0) precedes it). -> no write-under-read.
//   * vmcnt(8) at iter s end: outstanding <= 12 (stages issued at s, s-1,
//     s-2); completing to 8 drains the OLDEST 4 = sub-tile s+1's loads;
//     barrier makes that global. Induction base: prologue stages 0,1,2 then
//     vmcnt(8) drains sub-tile 0. vmcnt never 0 in the loop (T4).
//
// LDS swizzle (T2, 64-B rows) — MEASURED 0 CONFLICTS, do not modify:
//   read slot = (lhi ^ ((l16>>1)&3))*16; stage gcol = ((lane&3)^((lane>>3)&3))*16
// ---------------------------------------------------------------------------
__global__ __launch_bounds__(512, 2) void gemm_i8(
    const int8_t* __restrict__ Aq,   // [M][K]
    const int8_t* __restrict__ Wt,   // [N][K]
    const unsigned int* __restrict__ maxbits,
    const float* __restrict__ wscale,  // [N]
    const float* __restrict__ bias,    // [N]
    float* __restrict__ out) {         // [M][N]
  __shared__ int8_t lds[4 * BUF_BYTES];

  const int tid = threadIdx.x;
  const int lane = tid & 63;
  const int wid = tid >> 6;      // 0..7
  const int l16 = lane & 15;
  const int lhi = lane >> 4;     // 0..3

  // T1: XCD-aware block swizzle. 512 blocks, 512 % 8 == 0 -> bijective.
  const int flat = blockIdx.y * gridDim.x + blockIdx.x;
  const int swz = (flat & 7) * 64 + (flat >> 3);
  const int m0 = (swz / (N_TOT / BN)) * BM;
  const int n0 = (swz % (N_TOT / BN)) * BN;

  const int wave_m = wid >> 2;   // 0..1  -> 128 rows
  const int wave_n = wid & 3;    // 0..3  -> 64 cols

  // ---- staging: per wave 2 A-chunks + 2 B-chunks, 1 KB each (16 rows x 64 B)
  const int row_l = lane >> 2;                             // row in chunk 0..15
  const int gcol = ((lane & 3) ^ ((lane >> 3) & 3)) << 4;  // pre-swizzled slot
  const int8_t* Abase = Aq + (size_t)m0 * K_TOT;           // uniform
  const int8_t* Bbase = Wt + (size_t)n0 * K_TOT;           // uniform
  int goff[2];
#pragma unroll
  for (int c = 0; c < 2; ++c) {
    int grow = (wid * 2 + c) * 16 + row_l;                 // 0..255
    goff[c] = grow * K_TOT + gcol;
  }

  auto stage = [&](int dstbuf, int koff) {
#pragma unroll
    for (int c = 0; c < 2; ++c) {
      __builtin_amdgcn_global_load_lds(
          (const __attribute__((address_space(1))) void*)(Abase + goff[c] + koff),
          (__attribute__((address_space(3))) void*)(lds + dstbuf * BUF_BYTES + (wid * 2 + c) * 1024),
          16, 0, 0);
      __builtin_amdgcn_global_load_lds(
          (const __attribute__((address_space(1))) void*)(Bbase + goff[c] + koff),
          (__attribute__((address_space(3))) void*)(lds + dstbuf * BUF_BYTES + A_SUB + (wid * 2 + c) * 1024),
          16, 0, 0);
    }
  };

  // ---- ds_read fragment addressing (swizzled, 64-B rows) ----
  const int slot = (lhi ^ ((l16 >> 1) & 3)) << 4;
  const int aOff = (wave_m * 128 + l16) * SUB + slot;
  const int bOff = (wave_n * 64 + l16) * SUB + slot;

  // ---- prologue: stage sub-tiles 0,1,2; drain sub-tile 0 ----
  stage(0, 0);
  stage(1, SUB);
  stage(2, 2 * SUB);
  asm volatile("s_waitcnt vmcnt(8)" ::: "memory");
  __builtin_amdgcn_s_barrier();
  __builtin_amdgcn_sched_barrier(0);

  v4i acc[8][4] = {};

#pragma unroll 4
  for (int s = 0; s < NS; ++s) {
    const int buf = s & 3;
    const int8_t* Ab = lds + buf * BUF_BYTES;
    const int8_t* Bb = Ab + A_SUB;

    // 12 ds_read_b128 — b's FIRST so MFMA group 0 is eligible after 5 reads
    v4i a[8], b[4];
#pragma unroll
    for (int j = 0; j < 4; ++j) b[j] = *(const v4i*)(Bb + bOff + j * 1024);
#pragma unroll
    for (int i = 0; i < 8; ++i) a[i] = *(const v4i*)(Ab + aOff + i * 1024);

    // prefetch sub-tile s+3 into the buffer drained at iter s-1
    const int ts = (s + 3 < NS) ? (s + 3) : (NS - 1);
    stage((s + 3) & 3, ts * SUB);

    __builtin_amdgcn_s_setprio(1);
#pragma unroll
    for (int i = 0; i < 8; ++i)
#pragma unroll
      for (int j = 0; j < 4; ++j)
        acc[i][j] = __builtin_amdgcn_mfma_i32_16x16x64_i8(a[i], b[j], acc[i][j], 0, 0, 0);
    __builtin_amdgcn_s_setprio(0);
    __builtin_amdgcn_sched_barrier(0);

    asm volatile("s_waitcnt lgkmcnt(0)" ::: "memory");
    asm volatile("s_waitcnt vmcnt(8)" ::: "memory");
    __builtin_amdgcn_sched_barrier(0);
    __builtin_amdgcn_s_barrier();
    __builtin_amdgcn_sched_barrier(0);
  }

  // ---- epilogue: dequant + bias, C/D layout col=l16, row=lhi*4+reg ----
  const float ascale = __uint_as_float(*maxbits) / 127.0f;
#pragma unroll
  for (int i = 0; i < 8; ++i) {
    const int orow = m0 + wave_m * 128 + i * 16 + lhi * 4;
#pragma unroll
    for (int j = 0; j < 4; ++j) {
      const int ocol = n0 + wave_n * 64 + j * 16 + l16;
      const float wsc = wscale[ocol] * ascale;
      const float bb = bias[ocol];
#pragma unroll
      for (int r = 0; r < 4; ++r) {
        out[(size_t)(orow + r) * N_TOT + ocol] = (float)acc[i][j][r] * wsc + bb;
      }
    }
  }
}

// ---------------------------------------------------------------------------
extern "C" void kernel_launch(void* const* d_in, const int* in_sizes, int n_in,
                              void* d_out, int out_size, void* d_ws, size_t ws_size,
                              hipStream_t stream) {
  const float* x = (const float*)d_in[0];
  const int* w32 = (const int*)d_in[1];        // int8 in reference, int32 on device
  const float* wscale = (const float*)d_in[2];
  const float* smooth = (const float*)d_in[3];
  const float* bias = (const float*)d_in[4];
  float* out = (float*)d_out;

  unsigned int* maxbits = (unsigned int*)d_ws;
  float* partials = (float*)((char*)d_ws + 1024);            // NPREP floats
  int8_t* xq = (int8_t*)d_ws + (1 << 20);                    // 32 MB
  int8_t* wq8 = xq + (size_t)M_TOT * K_TOT;                  // 16 MB

  const int nw4 = N_TOT * K_TOT / 4;
  const int n4 = M_TOT * K_TOT / 4;
  prep_reduce<<<NPREP, 256, 0, stream>>>((const int4*)w32, (int*)wq8, nw4,
                                         (const float4*)smooth, (const float4*)x,
                                         partials, n4);
  quantize_x<<<2048, 256, 0, stream>>>((const float4*)x, (const float4*)smooth,
                                       partials, maxbits, (int*)xq, n4);

  dim3 grid(N_TOT / BN, M_TOT / BM);
  gemm_i8<<<grid, 512, 0, stream>>>(xq, wq8, maxbits, wscale, bias, out);
}